// Round 19
// baseline (383.946 us; speedup 1.0000x reference)
//
#include <hip/hip_runtime.h>
#include <hip/hip_bf16.h>

typedef unsigned short u16;
typedef __bf16 bf16x8 __attribute__((ext_vector_type(8)));
typedef float floatx4 __attribute__((ext_vector_type(4)));

__device__ __forceinline__ float bf2f_u(u16 u) {
    union { unsigned int i; float f; } x; x.i = ((unsigned int)u) << 16; return x.f;
}
__device__ __forceinline__ u16 f2bf_u(float f) {
    union { float f; unsigned int i; } x; x.f = f;
    unsigned int r = x.i + 0x7fffu + ((x.i >> 16) & 1u);   // RNE
    return (u16)(r >> 16);
}

// async global->LDS, 16 B/lane, LDS dest = wave-uniform base + lane*16
__device__ __forceinline__ void gl_lds16(const void* g, void* l) {
    __builtin_amdgcn_global_load_lds(
        (const __attribute__((address_space(1))) void*)g,
        (__attribute__((address_space(3))) void*)l, 16, 0, 0);
}

// ---------------------------------------------------------------------------
// Fused prep kernel: replaces 4x transpose + tobf (5 launches -> 1).
__device__ __forceinline__ void transpose_body(
    const float* __restrict__ ip, u16* __restrict__ op,
    int R, int C, int r0, int c0, int t, u16 (*T)[80])
{
#pragma unroll
    for (int i = 0; i < 4; i++) {
        int c = t + i * 256;
        int rr = c >> 4, cc = (c & 15) * 4;
        float4 v = *(const float4*)&ip[(size_t)(r0 + rr) * C + c0 + cc];
        T[cc + 0][rr] = f2bf_u(v.x); T[cc + 1][rr] = f2bf_u(v.y);
        T[cc + 2][rr] = f2bf_u(v.z); T[cc + 3][rr] = f2bf_u(v.w);
    }
    __syncthreads();
#pragma unroll
    for (int i = 0; i < 2; i++) {
        int c = t + i * 256;
        int oc = c >> 3, k8 = (c & 7) * 8;
        uint4 v = *(const uint4*)&T[oc][k8];
        *(uint4*)&op[(size_t)(c0 + oc) * R + r0 + k8] = v;
    }
}

__global__ __launch_bounds__(256) void prep_k(
    const float* __restrict__ x,    u16* __restrict__ x_bf,
    const float* __restrict__ w1,   u16* __restrict__ w1_bt,
    const float* __restrict__ w2,   u16* __restrict__ w2_bt,
    const float* __restrict__ wq_w, u16* __restrict__ wqm_bt,
    const float* __restrict__ fc_w, u16* __restrict__ fcw_bt)
{
    __shared__ u16 T[64][80];
    const int id = blockIdx.x, t = threadIdx.x;
    if (id < 2048) {
        int i = (id * 256 + t) * 8;
        float4 v0 = *(const float4*)&x[i];
        float4 v1 = *(const float4*)&x[i + 4];
        u16 tmp[8] = {f2bf_u(v0.x), f2bf_u(v0.y), f2bf_u(v0.z), f2bf_u(v0.w),
                      f2bf_u(v1.x), f2bf_u(v1.y), f2bf_u(v1.z), f2bf_u(v1.w)};
        *(uint4*)&x_bf[i] = *(const uint4*)tmp;
    } else if (id < 3072) {
        int j = id - 2048;                       // grid (64,16)
        transpose_body(w1, w1_bt, 1024, 4096, (j >> 6) * 64, (j & 63) * 64, t, T);
    } else if (id < 4096) {
        int j = id - 3072;                       // grid (16,64)
        transpose_body(w2, w2_bt, 4096, 1024, (j >> 4) * 64, (j & 15) * 64, t, T);
    } else if (id < 4352) {
        int j = id - 4096;                       // grid (1,16,16): y=j&15, z=j>>4
        int z = j >> 4;
        transpose_body(wq_w + (size_t)z * (1024 * 64),
                       wqm_bt + (size_t)z * (64 * 1024),
                       1024, 64, (j & 15) * 64, 0, t, T);
    } else {
        int j = id - 4352;                       // grid (16,16)
        transpose_body(fc_w, fcw_bt, 1024, 1024, (j >> 4) * 64, (j & 15) * 64, t, T);
    }
}

// ---------------------------------------------------------------------------
// bf16 transpose for attention V: qhT[bh][d][s] = qh[bh][s][d].
__global__ __launch_bounds__(256) void transpose_qh_k(const u16* __restrict__ in,
                                                      u16* __restrict__ out)
{
    __shared__ u16 T[64][72];            // 72*2B = 144 B row = 9x16B (aligned)
    const int bh = blockIdx.y;
    const int s0 = blockIdx.x * 64;
    const u16* ip = in + (size_t)bh * (2048 * 64);
    u16* op = out + (size_t)bh * (64 * 2048);
    const int t = threadIdx.x;
#pragma unroll
    for (int i = 0; i < 2; i++) {
        int c = t + i * 256;             // 512 chunks of 8 u16
        int r = c >> 3, cc = (c & 7) * 8;
        uint4 v = *(const uint4*)&ip[(size_t)(s0 + r) * 64 + cc];
        const u16* pv = (const u16*)&v;
#pragma unroll
        for (int k = 0; k < 8; k++) T[cc + k][r] = pv[k];
    }
    __syncthreads();
#pragma unroll
    for (int i = 0; i < 2; i++) {
        int c = t + i * 256;
        int d = c >> 3, cs = (c & 7) * 8;
        uint4 v = *(const uint4*)&T[d][cs];
        *(uint4*)&op[(size_t)d * 2048 + s0 + cs] = v;
    }
}

// ---------------------------------------------------------------------------
// Shared epilogue (4x2 acc) for BM=128 GEMMs.
__device__ __forceinline__ void gemm_epilogue(
    floatx4 (&acc)[4][2], int m0, int n0, int wm, int wn, int lr, int quad,
    int N, const float* __restrict__ bias, const u16* __restrict__ resid,
    float* __restrict__ out, u16* __restrict__ out_bf, int mode)
{
#pragma unroll
    for (int i = 0; i < 4; i++) {
#pragma unroll
        for (int j = 0; j < 2; j++) {
#pragma unroll
            for (int r = 0; r < 4; r++) {
                int grow = m0 + wm + i * 16 + quad * 4 + r;
                int gcol = n0 + wn + j * 16 + lr;
                float val = acc[i][j][r];
                if (bias) val += bias[gcol];
                if (mode == 0) {
                    int bb = grow >> 11, ss = grow & 2047;
                    int h = gcol >> 6, e = gcol & 63;
                    out_bf[(((size_t)bb * 16 + h) * 2048 + ss) * 64 + e] = f2bf_u(val);
                } else if (mode == 1) {
                    size_t idx = (size_t)grow * N + gcol;
                    out[idx] = val + bf2f_u(resid[idx]);
                } else if (mode == 2) {
                    out_bf[(size_t)grow * N + gcol] = f2bf_u(fmaxf(val, 0.f));
                } else if (mode == 3) {
                    size_t idx = (size_t)grow * N + gcol;
                    out[idx] = out[idx] + val;
                } else {  // mode 4
                    size_t idx = (size_t)grow * N + gcol;
                    out_bf[idx] = f2bf_u(val + bf2f_u(resid[idx]));
                }
            }
        }
    }
}

// ---------------------------------------------------------------------------
// Depth-3 counted-vmcnt BM=128 variant (qproj / fc). 72 KB LDS, 2 blocks/CU.
__global__ __launch_bounds__(256) void gemm_bt64p3_k(
    const u16* __restrict__ A, const u16* __restrict__ Bt,
    int gm, int gn, int N, int K, int ldb,
    const float* __restrict__ bias, const u16* __restrict__ resid,
    float* __restrict__ out, u16* __restrict__ out_bf, int mode)
{
    __shared__ __align__(16) u16 As[3][128 * 64];
    __shared__ __align__(16) u16 Bs[3][64 * 64];

    const int id = blockIdx.x;
    const int xcd = id & 7, s = id >> 3;
    const int bandM = gm >> 2, bandN = gn >> 1;
    const int m0 = ((xcd >> 1) * bandM + (s % bandM)) * 128;
    const int n0 = ((xcd & 1) * bandN + (s / bandM)) * 64;

    const int t = threadIdx.x;
    const int wid = t >> 6, lane = t & 63;
    const int wm = (wid >> 1) * 64, wn = (wid & 1) * 32;
    const int lr = lane & 15, quad = lane >> 4;
    const int srow = lane >> 3;
    const int scol = ((lane & 7) ^ (lane >> 3)) * 8;

    floatx4 acc[4][2];
#pragma unroll
    for (int i = 0; i < 4; i++)
#pragma unroll
        for (int j = 0; j < 2; j++)
            acc[i][j] = (floatx4){0.f, 0.f, 0.f, 0.f};

    auto stage = [&](int b, int k0) {
#pragma unroll
        for (int i = 0; i < 4; i++) {
            int rb = wid * 32 + i * 8;
            gl_lds16(&A[(size_t)(m0 + rb + srow) * K + k0 + scol], &As[b][rb * 64]);
        }
#pragma unroll
        for (int i = 0; i < 2; i++) {
            int rb = wid * 16 + i * 8;
            gl_lds16(&Bt[(size_t)(n0 + rb + srow) * ldb + k0 + scol], &Bs[b][rb * 64]);
        }
    };

    const int nt = K >> 6;
    stage(0, 0);
    stage(1, 64);

    int cur = 0, nxt = 2;
    for (int tt = 0; tt < nt; tt++) {
        if (tt + 1 < nt) asm volatile("s_waitcnt vmcnt(6)" ::: "memory");
        else             asm volatile("s_waitcnt vmcnt(0)" ::: "memory");
        __builtin_amdgcn_s_barrier();
        __builtin_amdgcn_sched_barrier(0);
        if (tt + 2 < nt) stage(nxt, (tt + 2) * 64);

#pragma unroll
        for (int kk = 0; kk < 2; kk++) {
            bf16x8 af[4], bfr[2];
#pragma unroll
            for (int i = 0; i < 4; i++) {
                int R = wm + i * 16 + lr;
                int c = ((kk * 4 + quad) ^ (lr & 7)) * 8;
                af[i] = *(const bf16x8*)&As[cur][R * 64 + c];
            }
#pragma unroll
            for (int j = 0; j < 2; j++) {
                int R = wn + j * 16 + lr;
                int c = ((kk * 4 + quad) ^ (lr & 7)) * 8;
                bfr[j] = *(const bf16x8*)&Bs[cur][R * 64 + c];
            }
#pragma unroll
            for (int i = 0; i < 4; i++)
#pragma unroll
                for (int j = 0; j < 2; j++)
                    acc[i][j] = __builtin_amdgcn_mfma_f32_16x16x32_bf16(af[i], bfr[j], acc[i][j], 0, 0, 0);
        }
        cur = (cur == 2) ? 0 : cur + 1;
        nxt = (nxt == 2) ? 0 : nxt + 1;
    }

    gemm_epilogue(acc, m0, n0, wm, wn, lr, quad, N, bias, resid, out, out_bf, mode);
}

// ---------------------------------------------------------------------------
// BM=64/BN=64 double-buffered GEMM (mlp1 AND mlp2). Block TLP is the lever
// (r16/r17): 32 KB LDS dbuf -> up to 5 resident blocks/CU.
__global__ __launch_bounds__(256) void gemm_bt64m_k(
    const u16* __restrict__ A, const u16* __restrict__ Bt,
    int gm, int gn, int N, int K, int ldb,
    const float* __restrict__ bias, const u16* __restrict__ resid,
    float* __restrict__ out, u16* __restrict__ out_bf, int mode)
{
    __shared__ __align__(16) u16 As[2][64 * 64];
    __shared__ __align__(16) u16 Bs[2][64 * 64];

    // XCD swizzle: gm x gn tile grid, 8 rectangles
    const int id = blockIdx.x;
    const int xcd = id & 7, s = id >> 3;
    const int bandM = gm >> 2, bandN = gn >> 1;
    const int m0 = ((xcd >> 1) * bandM + (s % bandM)) * 64;
    const int n0 = ((xcd & 1) * bandN + (s / bandM)) * 64;

    const int t = threadIdx.x;
    const int wid = t >> 6, lane = t & 63;
    const int wm = (wid >> 1) * 32, wn = (wid & 1) * 32;
    const int lr = lane & 15, quad = lane >> 4;
    const int srow = lane >> 3;
    const int scol = ((lane & 7) ^ (lane >> 3)) * 8;   // inverse-swizzled source

    floatx4 acc[2][2];
#pragma unroll
    for (int i = 0; i < 2; i++)
#pragma unroll
        for (int j = 0; j < 2; j++)
            acc[i][j] = (floatx4){0.f, 0.f, 0.f, 0.f};

    auto stage = [&](int b, int k0) {
#pragma unroll
        for (int i = 0; i < 2; i++) {                  // A: 64 rows, 2/wave
            int rb = wid * 16 + i * 8;
            gl_lds16(&A[(size_t)(m0 + rb + srow) * K + k0 + scol], &As[b][rb * 64]);
        }
#pragma unroll
        for (int i = 0; i < 2; i++) {                  // B: 64 rows, 2/wave
            int rb = wid * 16 + i * 8;
            gl_lds16(&Bt[(size_t)(n0 + rb + srow) * ldb + k0 + scol], &Bs[b][rb * 64]);
        }
    };

    const int nt = K >> 6;
    stage(0, 0);

    int cur = 0;
    for (int tt = 0; tt < nt; tt++) {
        asm volatile("s_waitcnt vmcnt(0)" ::: "memory");
        __builtin_amdgcn_s_barrier();
        __builtin_amdgcn_sched_barrier(0);
        if (tt + 1 < nt) stage(cur ^ 1, (tt + 1) * 64);

#pragma unroll
        for (int kk = 0; kk < 2; kk++) {
            bf16x8 af[2], bfr[2];
#pragma unroll
            for (int i = 0; i < 2; i++) {
                int R = wm + i * 16 + lr;
                int c = ((kk * 4 + quad) ^ (lr & 7)) * 8;
                af[i] = *(const bf16x8*)&As[cur][R * 64 + c];
            }
#pragma unroll
            for (int j = 0; j < 2; j++) {
                int R = wn + j * 16 + lr;
                int c = ((kk * 4 + quad) ^ (lr & 7)) * 8;
                bfr[j] = *(const bf16x8*)&Bs[cur][R * 64 + c];
            }
#pragma unroll
            for (int i = 0; i < 2; i++)
#pragma unroll
                for (int j = 0; j < 2; j++)
                    acc[i][j] = __builtin_amdgcn_mfma_f32_16x16x32_bf16(af[i], bfr[j], acc[i][j], 0, 0, 0);
        }
        cur ^= 1;
    }

    // epilogue (2x2 acc)
#pragma unroll
    for (int i = 0; i < 2; i++) {
#pragma unroll
        for (int j = 0; j < 2; j++) {
#pragma unroll
            for (int r = 0; r < 4; r++) {
                int grow = m0 + wm + i * 16 + quad * 4 + r;
                int gcol = n0 + wn + j * 16 + lr;
                float val = acc[i][j][r];
                if (bias) val += bias[gcol];
                if (mode == 1) {
                    size_t idx = (size_t)grow * N + gcol;
                    out[idx] = val + bf2f_u(resid[idx]);
                } else if (mode == 3) {
                    size_t idx = (size_t)grow * N + gcol;
                    out[idx] = out[idx] + val;
                } else {  // mode 2
                    out_bf[(size_t)grow * N + gcol] = f2bf_u(fmaxf(val, 0.f));
                }
            }
        }
    }
}

// ---------------------------------------------------------------------------
// MFMA flash attention v6: v5 structure (gl_lds16 dbuf K/V, swapped QK^T,
// packed P, setprio) + QBLK 128 -> 64. Retry of r12's occupancy split, now
// that the mechanism that killed it (Vt scatter duplication, conflicts 2x)
// is gone: staging is conflict-free gl_lds16 with near-zero VALU, so
// halving QBLK only duplicates cheap L2-resident reads. r18 counters:
// VALU 47%, MFMA 20%, Occ 18.5% (2 blk/CU) -> dependency-bound; grid 1024,
// LDS 41.5 KB -> 3 blocks/CU (12 waves). Also folds the 0.125 scale into
// the exp2 constant (1 fewer v_mul per element; exp2f is native).
#define PST 68
__global__ __launch_bounds__(256) void attn_mfma_k(const u16* __restrict__ qh,
                                                   const u16* __restrict__ qhT,
                                                   u16* __restrict__ ctx)
{
    __shared__ __align__(16) u16 Ks[2][64 * 64];
    __shared__ __align__(16) u16 Vt[2][64 * 64];
    __shared__ __align__(16) u16 Ps[4][16][PST];

    const int bh = blockIdx.x >> 5;          // 32 q-blocks per (b,h)
    const int qb = blockIdx.x & 31;
    const u16* __restrict__ base  = qh  + (size_t)bh * (2048 * 64);
    const u16* __restrict__ baseT = qhT + (size_t)bh * (64 * 2048);
    const int t = threadIdx.x, wid = t >> 6, lane = t & 63;
    const int lr = lane & 15, quad = lane >> 4;
    const int q0 = qb * 64 + wid * 16;       // 16 q-rows per wave

    bf16x8 af0 = *(const bf16x8*)&base[(size_t)(q0 + lr) * 64 + quad * 8];
    bf16x8 af1 = *(const bf16x8*)&base[(size_t)(q0 + lr) * 64 + quad * 8 + 32];

    floatx4 Of[4];
#pragma unroll
    for (int dt = 0; dt < 4; dt++) Of[dt] = (floatx4){0.f, 0.f, 0.f, 0.f};
    float lsum = 0.f;                        // partial denom for q-row lr

    const int srow = lane >> 3;
    const int schk = (lane & 7) ^ srow;

    auto stage = [&](int b, int kt) {
#pragma unroll
        for (int i = 0; i < 2; i++) {
            int rb = (wid * 2 + i) * 8;
            gl_lds16(&base[(size_t)(kt + rb + srow) * 64 + schk * 8],
                     &Ks[b][rb * 64]);
            gl_lds16(&baseT[(size_t)(rb + srow) * 2048 + kt + schk * 8],
                     &Vt[b][rb * 64]);
        }
    };

    stage(0, 0);
    __syncthreads();

    // exp(z*0.125) = exp2(z * 0.125*log2e); clamp 60*log2e = 86.56
    const float C = 0.18033688011112042f;

    int buf = 0;
    for (int kt = 0; kt < 2048; kt += 64) {
        if (kt + 64 < 2048) stage(buf ^ 1, kt + 64);

#pragma unroll
        for (int nt = 0; nt < 4; nt++) {
            int row = nt * 16 + lr, rsw = row & 7;
            bf16x8 b0 = *(const bf16x8*)&Ks[buf][row * 64 + ((quad ^ rsw) * 8)];
            bf16x8 b1 = *(const bf16x8*)&Ks[buf][row * 64 + (((quad + 4) ^ rsw) * 8)];
            floatx4 z = (floatx4){0.f, 0.f, 0.f, 0.f};
            // swapped operands: z = S^T tile; lane holds k = nt*16+quad*4+r
            // (rows) for q-row = lr (col).
            z = __builtin_amdgcn_mfma_f32_16x16x32_bf16(b0, af0, z, 0, 0, 0);
            z = __builtin_amdgcn_mfma_f32_16x16x32_bf16(b1, af1, z, 0, 0, 0);
            float p0 = exp2f(fminf(z[0] * C, 86.56f));
            float p1 = exp2f(fminf(z[1] * C, 86.56f));
            float p2 = exp2f(fminf(z[2] * C, 86.56f));
            float p3 = exp2f(fminf(z[3] * C, 86.56f));
            lsum += (p0 + p1) + (p2 + p3);
            unsigned int lo, hi;
            asm("v_cvt_pk_bf16_f32 %0, %1, %2" : "=v"(lo) : "v"(p0), "v"(p1));
            asm("v_cvt_pk_bf16_f32 %0, %1, %2" : "=v"(hi) : "v"(p2), "v"(p3));
            uint2 pk; pk.x = lo; pk.y = hi;
            // P[q=lr][k = nt*16 + quad*4 .. +4], contiguous 8 B store
            *(uint2*)&Ps[wid][lr][nt * 16 + quad * 4] = pk;
        }

        bf16x8 aP0 = *(const bf16x8*)&Ps[wid][lr][quad * 8];
        bf16x8 aP1 = *(const bf16x8*)&Ps[wid][lr][quad * 8 + 32];
        __builtin_amdgcn_s_setprio(1);
#pragma unroll
        for (int dt = 0; dt < 4; dt++) {
            int d = dt * 16 + lr, dsw = d & 7;
            bf16x8 b0 = *(const bf16x8*)&Vt[buf][d * 64 + ((quad ^ dsw) * 8)];
            bf16x8 b1 = *(const bf16x8*)&Vt[buf][d * 64 + (((quad + 4) ^ dsw) * 8)];
            Of[dt] = __builtin_amdgcn_mfma_f32_16x16x32_bf16(aP0, b0, Of[dt], 0, 0, 0);
            Of[dt] = __builtin_amdgcn_mfma_f32_16x16x32_bf16(aP1, b1, Of[dt], 0, 0, 0);
        }
        __builtin_amdgcn_s_setprio(0);

        __syncthreads();
        buf ^= 1;
    }

    const int b = bh >> 4, h = bh & 15;
    float l = lsum;
    l += __shfl_xor(l, 16);
    l += __shfl_xor(l, 32);
#pragma unroll
    for (int r = 0; r < 4; r++) {
        float lq = __shfl(l, quad * 4 + r);
        float inv = 1.f / lq;
        size_t rowoff = ((size_t)b * 2048 + q0 + quad * 4 + r) * 1024 + h * 64;
#pragma unroll
        for (int dt = 0; dt < 4; dt++)
            ctx[rowoff + dt * 16 + lr] = f2bf_u(Of[dt][r] * inv);
    }
}

// ---------------------------------------------------------------------------
// LayerNorm D=1024; input bf16 (icode 0) or fp32 (icode 1); out fp32/bf16.
__global__ __launch_bounds__(256) void ln_k(const void* __restrict__ in,
                                            const float* __restrict__ g,
                                            const float* __restrict__ b,
                                            float* __restrict__ out_f,
                                            u16* __restrict__ out_bf, int icode)
{
    const int row = blockIdx.x;
    const int t = threadIdx.x;
    float4 v;
    if (icode) {
        v = *(const float4*)&((const float*)in)[(size_t)row * 1024 + t * 4];
    } else {
        ushort4 u = *(const ushort4*)&((const u16*)in)[(size_t)row * 1024 + t * 4];
        v.x = bf2f_u(u.x); v.y = bf2f_u(u.y); v.z = bf2f_u(u.z); v.w = bf2f_u(u.w);
    }
    float s  = v.x + v.y + v.z + v.w;
    float ss = v.x * v.x + v.y * v.y + v.z * v.z + v.w * v.w;
#pragma unroll
    for (int off = 32; off >= 1; off >>= 1) {
        s  += __shfl_down(s, off);
        ss += __shfl_down(ss, off);
    }
    __shared__ float sm[10];
    const int wid = t >> 6, lane = t & 63;
    if (lane == 0) { sm[wid] = s; sm[4 + wid] = ss; }
    __syncthreads();
    if (t == 0) {
        float S  = sm[0] + sm[1] + sm[2] + sm[3];
        float SS = sm[4] + sm[5] + sm[6] + sm[7];
        float mu = S * (1.f / 1024.f);
        float var = SS * (1.f / 1024.f) - mu * mu;
        sm[8] = mu; sm[9] = rsqrtf(fmaxf(var, 0.f) + 1e-5f);
    }
    __syncthreads();
    float mu = sm[8], rs = sm[9];
    float4 G  = *(const float4*)&g[t * 4];
    float4 Bv = *(const float4*)&b[t * 4];
    float r0 = (v.x - mu) * rs * G.x + Bv.x;
    float r1 = (v.y - mu) * rs * G.y + Bv.y;
    float r2 = (v.z - mu) * rs * G.z + Bv.z;
    float r3 = (v.w - mu) * rs * G.w + Bv.w;
    if (out_f) {
        float4 ov = {r0, r1, r2, r3};
        *(float4*)&out_f[(size_t)row * 1024 + t * 4] = ov;
    }
    if (out_bf) {
        ushort4 ou = {f2bf_u(r0), f2bf_u(r1), f2bf_u(r2), f2bf_u(r3)};
        *(ushort4*)&out_bf[(size_t)row * 1024 + t * 4] = ou;
    }
}

// ---------------------------------------------------------------------------
extern "C" void kernel_launch(void* const* d_in, const int* in_sizes, int n_in,
                              void* d_out, int out_size, void* d_ws, size_t ws_size,
                              hipStream_t stream)
{
    const float* x    = (const float*)d_in[0];
    const float* wq_w = (const float*)d_in[1];
    const float* wq_b = (const float*)d_in[2];
    const float* fc_w = (const float*)d_in[3];
    const float* fc_b = (const float*)d_in[4];
    const float* ln1g = (const float*)d_in[5];
    const float* ln1b = (const float*)d_in[6];
    const float* w1   = (const float*)d_in[7];
    const float* b1   = (const float*)d_in[8];
    const float* w2   = (const float*)d_in[9];
    const float* b2   = (const float*)d_in[10];
    const float* ln2g = (const float*)d_in[11];
    const float* ln2b = (const float*)d_in[12];

    // Workspace layout (see round-0 comment); qhT shares [44,52) with yfc_bf.
    char* ws = (char*)d_ws;
    const size_t MB = 1024 * 1024;
    u16*   w1_bt  = (u16*)(ws);
    u16*   w2_bt  = (u16*)(ws + 8 * MB);
    u16*   wqm_bt = (u16*)(ws + 16 * MB);
    u16*   fcw_bt = (u16*)(ws + 18 * MB);
    u16*   x_bf   = (u16*)(ws + 20 * MB);
    u16*   qh     = (u16*)(ws + 28 * MB);
    u16*   yln1   = (u16*)(ws + 28 * MB);
    u16*   ctx    = (u16*)(ws + 36 * MB);
    u16*   yfc_bf = (u16*)(ws + 44 * MB);
    u16*   qhT    = (u16*)(ws + 44 * MB);   // shared with yfc_bf (disjoint)
    u16*   h1     = (u16*)(ws + 36 * MB);   // full or chunk base
    float* z      = (float*)d_out;
    const bool fullN = ws_size >= 69 * MB;

    // fused prep: 4 transposes + tobf in one launch
    prep_k<<<4608, 256, 0, stream>>>(x, x_bf, w1, w1_bt, w2, w2_bt,
                                     wq_w, wqm_bt, fc_w, fcw_bt);

    // qproj: x_bf @ wqm_bt^T + wq_b -> qh scatter   (depth-3, 512 blk)
    gemm_bt64p3_k<<<512, 256, 0, stream>>>(x_bf, wqm_bt, 32, 16, 1024, 1024, 1024,
                                           wq_b, nullptr, nullptr, qh, 0);
    // V transpose for attn: qhT[bh][d][s]
    transpose_qh_k<<<dim3(32, 32), 256, 0, stream>>>(qh, qhT);
    // attn v6: QBLK=64, grid 1024 = 3 blocks/CU
    attn_mfma_k<<<1024, 256, 0, stream>>>(qh, qhT, ctx);
    // fc: ctx @ fcw_bt^T + fc_b + x_bf -> yfc_bf    (depth-3, 512 blk)
    gemm_bt64p3_k<<<512, 256, 0, stream>>>(ctx, fcw_bt, 32, 16, 1024, 1024, 1024,
                                           fc_b, x_bf, nullptr, yfc_bf, 4);
    ln_k<<<4096, 256, 0, stream>>>(yfc_bf, ln1g, ln1b, nullptr, yln1, 0);

    if (fullN) {
        // mlp1: yln1 @ w1_bt^T -> relu -> h1 [4096,4096]
        // (BM=64: gm=64 gn=64, grid 4096 = 5 resident blocks/CU)
        gemm_bt64m_k<<<4096, 256, 0, stream>>>(yln1, w1_bt, 64, 64, 4096, 1024, 1024,
                                               b1, nullptr, nullptr, h1, 2);
        // mlp2: h1 @ w2_bt^T + b2 + yln1 -> z fp32
        // (BM=64: gm=64 gn=16, grid 1024 = 4 blocks/CU)
        gemm_bt64m_k<<<1024, 256, 0, stream>>>(h1, w2_bt, 64, 16, 1024, 4096, 4096,
                                               b2, yln1, z, nullptr, 1);
    } else {
        gemm_bt64m_k<<<2048, 256, 0, stream>>>(yln1, w1_bt, 64, 32, 2048, 1024, 1024,
                                               b1, nullptr, nullptr, h1, 2);
        gemm_bt64m_k<<<1024, 256, 0, stream>>>(h1, w2_bt, 64, 16, 1024, 2048, 4096,
                                               b2, yln1, z, nullptr, 1);
        gemm_bt64m_k<<<2048, 256, 0, stream>>>(yln1, w1_bt + (size_t)2048 * 1024, 64, 32,
                                               2048, 1024, 1024,
                                               b1 + 2048, nullptr, nullptr, h1, 2);
        gemm_bt64m_k<<<1024, 256, 0, stream>>>(h1, w2_bt + 2048, 64, 16, 1024, 2048, 4096,
                                               nullptr, nullptr, z, nullptr, 3);
    }
    ln_k<<<4096, 256, 0, stream>>>(z, ln2g, ln2b, (float*)d_out, nullptr, 1);
}

// Round 20
// 374.778 us; speedup vs baseline: 1.0245x; 1.0245x over previous
//
#include <hip/hip_runtime.h>
#include <hip/hip_bf16.h>

typedef unsigned short u16;
typedef __bf16 bf16x8 __attribute__((ext_vector_type(8)));
typedef float floatx4 __attribute__((ext_vector_type(4)));

__device__ __forceinline__ float bf2f_u(u16 u) {
    union { unsigned int i; float f; } x; x.i = ((unsigned int)u) << 16; return x.f;
}
__device__ __forceinline__ u16 f2bf_u(float f) {
    union { float f; unsigned int i; } x; x.f = f;
    unsigned int r = x.i + 0x7fffu + ((x.i >> 16) & 1u);   // RNE
    return (u16)(r >> 16);
}

// async global->LDS, 16 B/lane, LDS dest = wave-uniform base + lane*16
__device__ __forceinline__ void gl_lds16(const void* g, void* l) {
    __builtin_amdgcn_global_load_lds(
        (const __attribute__((address_space(1))) void*)g,
        (__attribute__((address_space(3))) void*)l, 16, 0, 0);
}

// ---------------------------------------------------------------------------
// Fused prep kernel: replaces 4x transpose + tobf (5 launches -> 1).
__device__ __forceinline__ void transpose_body(
    const float* __restrict__ ip, u16* __restrict__ op,
    int R, int C, int r0, int c0, int t, u16 (*T)[80])
{
#pragma unroll
    for (int i = 0; i < 4; i++) {
        int c = t + i * 256;
        int rr = c >> 4, cc = (c & 15) * 4;
        float4 v = *(const float4*)&ip[(size_t)(r0 + rr) * C + c0 + cc];
        T[cc + 0][rr] = f2bf_u(v.x); T[cc + 1][rr] = f2bf_u(v.y);
        T[cc + 2][rr] = f2bf_u(v.z); T[cc + 3][rr] = f2bf_u(v.w);
    }
    __syncthreads();
#pragma unroll
    for (int i = 0; i < 2; i++) {
        int c = t + i * 256;
        int oc = c >> 3, k8 = (c & 7) * 8;
        uint4 v = *(const uint4*)&T[oc][k8];
        *(uint4*)&op[(size_t)(c0 + oc) * R + r0 + k8] = v;
    }
}

__global__ __launch_bounds__(256) void prep_k(
    const float* __restrict__ x,    u16* __restrict__ x_bf,
    const float* __restrict__ w1,   u16* __restrict__ w1_bt,
    const float* __restrict__ w2,   u16* __restrict__ w2_bt,
    const float* __restrict__ wq_w, u16* __restrict__ wqm_bt,
    const float* __restrict__ fc_w, u16* __restrict__ fcw_bt)
{
    __shared__ u16 T[64][80];
    const int id = blockIdx.x, t = threadIdx.x;
    if (id < 2048) {
        int i = (id * 256 + t) * 8;
        float4 v0 = *(const float4*)&x[i];
        float4 v1 = *(const float4*)&x[i + 4];
        u16 tmp[8] = {f2bf_u(v0.x), f2bf_u(v0.y), f2bf_u(v0.z), f2bf_u(v0.w),
                      f2bf_u(v1.x), f2bf_u(v1.y), f2bf_u(v1.z), f2bf_u(v1.w)};
        *(uint4*)&x_bf[i] = *(const uint4*)tmp;
    } else if (id < 3072) {
        int j = id - 2048;                       // grid (64,16)
        transpose_body(w1, w1_bt, 1024, 4096, (j >> 6) * 64, (j & 63) * 64, t, T);
    } else if (id < 4096) {
        int j = id - 3072;                       // grid (16,64)
        transpose_body(w2, w2_bt, 4096, 1024, (j >> 4) * 64, (j & 15) * 64, t, T);
    } else if (id < 4352) {
        int j = id - 4096;                       // grid (1,16,16): y=j&15, z=j>>4
        int z = j >> 4;
        transpose_body(wq_w + (size_t)z * (1024 * 64),
                       wqm_bt + (size_t)z * (64 * 1024),
                       1024, 64, (j & 15) * 64, 0, t, T);
    } else {
        int j = id - 4352;                       // grid (16,16)
        transpose_body(fc_w, fcw_bt, 1024, 1024, (j >> 4) * 64, (j & 15) * 64, t, T);
    }
}

// ---------------------------------------------------------------------------
// bf16 transpose for attention V: qhT[bh][d][s] = qh[bh][s][d].
__global__ __launch_bounds__(256) void transpose_qh_k(const u16* __restrict__ in,
                                                      u16* __restrict__ out)
{
    __shared__ u16 T[64][72];            // 72*2B = 144 B row = 9x16B (aligned)
    const int bh = blockIdx.y;
    const int s0 = blockIdx.x * 64;
    const u16* ip = in + (size_t)bh * (2048 * 64);
    u16* op = out + (size_t)bh * (64 * 2048);
    const int t = threadIdx.x;
#pragma unroll
    for (int i = 0; i < 2; i++) {
        int c = t + i * 256;             // 512 chunks of 8 u16
        int r = c >> 3, cc = (c & 7) * 8;
        uint4 v = *(const uint4*)&ip[(size_t)(s0 + r) * 64 + cc];
        const u16* pv = (const u16*)&v;
#pragma unroll
        for (int k = 0; k < 8; k++) T[cc + k][r] = pv[k];
    }
    __syncthreads();
#pragma unroll
    for (int i = 0; i < 2; i++) {
        int c = t + i * 256;
        int d = c >> 3, cs = (c & 7) * 8;
        uint4 v = *(const uint4*)&T[d][cs];
        *(uint4*)&op[(size_t)d * 2048 + s0 + cs] = v;
    }
}

// ---------------------------------------------------------------------------
// Shared epilogue (4x2 acc) for BM=128 GEMMs.
__device__ __forceinline__ void gemm_epilogue(
    floatx4 (&acc)[4][2], int m0, int n0, int wm, int wn, int lr, int quad,
    int N, const float* __restrict__ bias, const u16* __restrict__ resid,
    float* __restrict__ out, u16* __restrict__ out_bf, int mode)
{
#pragma unroll
    for (int i = 0; i < 4; i++) {
#pragma unroll
        for (int j = 0; j < 2; j++) {
#pragma unroll
            for (int r = 0; r < 4; r++) {
                int grow = m0 + wm + i * 16 + quad * 4 + r;
                int gcol = n0 + wn + j * 16 + lr;
                float val = acc[i][j][r];
                if (bias) val += bias[gcol];
                if (mode == 0) {
                    int bb = grow >> 11, ss = grow & 2047;
                    int h = gcol >> 6, e = gcol & 63;
                    out_bf[(((size_t)bb * 16 + h) * 2048 + ss) * 64 + e] = f2bf_u(val);
                } else if (mode == 1) {
                    size_t idx = (size_t)grow * N + gcol;
                    out[idx] = val + bf2f_u(resid[idx]);
                } else if (mode == 2) {
                    out_bf[(size_t)grow * N + gcol] = f2bf_u(fmaxf(val, 0.f));
                } else if (mode == 3) {
                    size_t idx = (size_t)grow * N + gcol;
                    out[idx] = out[idx] + val;
                } else {  // mode 4
                    size_t idx = (size_t)grow * N + gcol;
                    out_bf[idx] = f2bf_u(val + bf2f_u(resid[idx]));
                }
            }
        }
    }
}

// ---------------------------------------------------------------------------
// Depth-3 counted-vmcnt BM=128 variant (qproj / fc). 72 KB LDS, 2 blocks/CU.
__global__ __launch_bounds__(256) void gemm_bt64p3_k(
    const u16* __restrict__ A, const u16* __restrict__ Bt,
    int gm, int gn, int N, int K, int ldb,
    const float* __restrict__ bias, const u16* __restrict__ resid,
    float* __restrict__ out, u16* __restrict__ out_bf, int mode)
{
    __shared__ __align__(16) u16 As[3][128 * 64];
    __shared__ __align__(16) u16 Bs[3][64 * 64];

    const int id = blockIdx.x;
    const int xcd = id & 7, s = id >> 3;
    const int bandM = gm >> 2, bandN = gn >> 1;
    const int m0 = ((xcd >> 1) * bandM + (s % bandM)) * 128;
    const int n0 = ((xcd & 1) * bandN + (s / bandM)) * 64;

    const int t = threadIdx.x;
    const int wid = t >> 6, lane = t & 63;
    const int wm = (wid >> 1) * 64, wn = (wid & 1) * 32;
    const int lr = lane & 15, quad = lane >> 4;
    const int srow = lane >> 3;
    const int scol = ((lane & 7) ^ (lane >> 3)) * 8;

    floatx4 acc[4][2];
#pragma unroll
    for (int i = 0; i < 4; i++)
#pragma unroll
        for (int j = 0; j < 2; j++)
            acc[i][j] = (floatx4){0.f, 0.f, 0.f, 0.f};

    auto stage = [&](int b, int k0) {
#pragma unroll
        for (int i = 0; i < 4; i++) {
            int rb = wid * 32 + i * 8;
            gl_lds16(&A[(size_t)(m0 + rb + srow) * K + k0 + scol], &As[b][rb * 64]);
        }
#pragma unroll
        for (int i = 0; i < 2; i++) {
            int rb = wid * 16 + i * 8;
            gl_lds16(&Bt[(size_t)(n0 + rb + srow) * ldb + k0 + scol], &Bs[b][rb * 64]);
        }
    };

    const int nt = K >> 6;
    stage(0, 0);
    stage(1, 64);

    int cur = 0, nxt = 2;
    for (int tt = 0; tt < nt; tt++) {
        if (tt + 1 < nt) asm volatile("s_waitcnt vmcnt(6)" ::: "memory");
        else             asm volatile("s_waitcnt vmcnt(0)" ::: "memory");
        __builtin_amdgcn_s_barrier();
        __builtin_amdgcn_sched_barrier(0);
        if (tt + 2 < nt) stage(nxt, (tt + 2) * 64);

#pragma unroll
        for (int kk = 0; kk < 2; kk++) {
            bf16x8 af[4], bfr[2];
#pragma unroll
            for (int i = 0; i < 4; i++) {
                int R = wm + i * 16 + lr;
                int c = ((kk * 4 + quad) ^ (lr & 7)) * 8;
                af[i] = *(const bf16x8*)&As[cur][R * 64 + c];
            }
#pragma unroll
            for (int j = 0; j < 2; j++) {
                int R = wn + j * 16 + lr;
                int c = ((kk * 4 + quad) ^ (lr & 7)) * 8;
                bfr[j] = *(const bf16x8*)&Bs[cur][R * 64 + c];
            }
#pragma unroll
            for (int i = 0; i < 4; i++)
#pragma unroll
                for (int j = 0; j < 2; j++)
                    acc[i][j] = __builtin_amdgcn_mfma_f32_16x16x32_bf16(af[i], bfr[j], acc[i][j], 0, 0, 0);
        }
        cur = (cur == 2) ? 0 : cur + 1;
        nxt = (nxt == 2) ? 0 : nxt + 1;
    }

    gemm_epilogue(acc, m0, n0, wm, wn, lr, quad, N, bias, resid, out, out_bf, mode);
}

// ---------------------------------------------------------------------------
// BM=64/BN=64 double-buffered GEMM (mlp1 AND mlp2). Block TLP is the lever
// (r16/r17): 32 KB LDS dbuf -> up to 5 resident blocks/CU.
__global__ __launch_bounds__(256) void gemm_bt64m_k(
    const u16* __restrict__ A, const u16* __restrict__ Bt,
    int gm, int gn, int N, int K, int ldb,
    const float* __restrict__ bias, const u16* __restrict__ resid,
    float* __restrict__ out, u16* __restrict__ out_bf, int mode)
{
    __shared__ __align__(16) u16 As[2][64 * 64];
    __shared__ __align__(16) u16 Bs[2][64 * 64];

    // XCD swizzle: gm x gn tile grid, 8 rectangles
    const int id = blockIdx.x;
    const int xcd = id & 7, s = id >> 3;
    const int bandM = gm >> 2, bandN = gn >> 1;
    const int m0 = ((xcd >> 1) * bandM + (s % bandM)) * 64;
    const int n0 = ((xcd & 1) * bandN + (s / bandM)) * 64;

    const int t = threadIdx.x;
    const int wid = t >> 6, lane = t & 63;
    const int wm = (wid >> 1) * 32, wn = (wid & 1) * 32;
    const int lr = lane & 15, quad = lane >> 4;
    const int srow = lane >> 3;
    const int scol = ((lane & 7) ^ (lane >> 3)) * 8;   // inverse-swizzled source

    floatx4 acc[2][2];
#pragma unroll
    for (int i = 0; i < 2; i++)
#pragma unroll
        for (int j = 0; j < 2; j++)
            acc[i][j] = (floatx4){0.f, 0.f, 0.f, 0.f};

    auto stage = [&](int b, int k0) {
#pragma unroll
        for (int i = 0; i < 2; i++) {                  // A: 64 rows, 2/wave
            int rb = wid * 16 + i * 8;
            gl_lds16(&A[(size_t)(m0 + rb + srow) * K + k0 + scol], &As[b][rb * 64]);
        }
#pragma unroll
        for (int i = 0; i < 2; i++) {                  // B: 64 rows, 2/wave
            int rb = wid * 16 + i * 8;
            gl_lds16(&Bt[(size_t)(n0 + rb + srow) * ldb + k0 + scol], &Bs[b][rb * 64]);
        }
    };

    const int nt = K >> 6;
    stage(0, 0);

    int cur = 0;
    for (int tt = 0; tt < nt; tt++) {
        asm volatile("s_waitcnt vmcnt(0)" ::: "memory");
        __builtin_amdgcn_s_barrier();
        __builtin_amdgcn_sched_barrier(0);
        if (tt + 1 < nt) stage(cur ^ 1, (tt + 1) * 64);

#pragma unroll
        for (int kk = 0; kk < 2; kk++) {
            bf16x8 af[2], bfr[2];
#pragma unroll
            for (int i = 0; i < 2; i++) {
                int R = wm + i * 16 + lr;
                int c = ((kk * 4 + quad) ^ (lr & 7)) * 8;
                af[i] = *(const bf16x8*)&As[cur][R * 64 + c];
            }
#pragma unroll
            for (int j = 0; j < 2; j++) {
                int R = wn + j * 16 + lr;
                int c = ((kk * 4 + quad) ^ (lr & 7)) * 8;
                bfr[j] = *(const bf16x8*)&Bs[cur][R * 64 + c];
            }
#pragma unroll
            for (int i = 0; i < 2; i++)
#pragma unroll
                for (int j = 0; j < 2; j++)
                    acc[i][j] = __builtin_amdgcn_mfma_f32_16x16x32_bf16(af[i], bfr[j], acc[i][j], 0, 0, 0);
        }
        cur ^= 1;
    }

    // epilogue (2x2 acc)
#pragma unroll
    for (int i = 0; i < 2; i++) {
#pragma unroll
        for (int j = 0; j < 2; j++) {
#pragma unroll
            for (int r = 0; r < 4; r++) {
                int grow = m0 + wm + i * 16 + quad * 4 + r;
                int gcol = n0 + wn + j * 16 + lr;
                float val = acc[i][j][r];
                if (bias) val += bias[gcol];
                if (mode == 1) {
                    size_t idx = (size_t)grow * N + gcol;
                    out[idx] = val + bf2f_u(resid[idx]);
                } else if (mode == 3) {
                    size_t idx = (size_t)grow * N + gcol;
                    out[idx] = out[idx] + val;
                } else {  // mode 2
                    out_bf[(size_t)grow * N + gcol] = f2bf_u(fmaxf(val, 0.f));
                }
            }
        }
    }
}

// ---------------------------------------------------------------------------
// MFMA flash attention v5r (r18 structure REVERTED from v6 — QBLK=64
// regressed twice: r12 (conflicts 2x) and r19 (conflicts 0, FETCH flat, yet
// +40%: each block stages the full 2048-deep K/V stream, so halving QBLK
// doubles total staging issues/barriers while halving the MFMA amortizing
// them; QBLK=128 is the measured amortization point). Keeps v6's exp2 fold
// (exp(z*.125) = exp2(z*0.18033688), clamp 86.56 == old 60 on exp arg).
#define PST 68
__global__ __launch_bounds__(256) void attn_mfma_k(const u16* __restrict__ qh,
                                                   const u16* __restrict__ qhT,
                                                   u16* __restrict__ ctx)
{
    __shared__ __align__(16) u16 Ks[2][64 * 64];
    __shared__ __align__(16) u16 Vt[2][64 * 64];
    __shared__ __align__(16) u16 Ps[4][2][16][PST];

    const int bh = blockIdx.x >> 4;
    const int qb = blockIdx.x & 15;
    const u16* __restrict__ base  = qh  + (size_t)bh * (2048 * 64);
    const u16* __restrict__ baseT = qhT + (size_t)bh * (64 * 2048);
    const int t = threadIdx.x, wid = t >> 6, lane = t & 63;
    const int lr = lane & 15, quad = lane >> 4;
    const int q0 = qb * 128 + wid * 16;

    bf16x8 af[2][2];
#pragma unroll
    for (int f = 0; f < 2; f++) {
        af[f][0] = *(const bf16x8*)&base[(size_t)(q0 + f * 64 + lr) * 64 + quad * 8];
        af[f][1] = *(const bf16x8*)&base[(size_t)(q0 + f * 64 + lr) * 64 + quad * 8 + 32];
    }

    floatx4 Of[2][4];
#pragma unroll
    for (int f = 0; f < 2; f++)
#pragma unroll
        for (int dt = 0; dt < 4; dt++) Of[f][dt] = (floatx4){0.f, 0.f, 0.f, 0.f};
    float lsum[2] = {0.f, 0.f};

    const int srow = lane >> 3;
    const int schk = (lane & 7) ^ srow;

    auto stage = [&](int b, int kt) {
#pragma unroll
        for (int i = 0; i < 2; i++) {
            int rb = (wid * 2 + i) * 8;
            gl_lds16(&base[(size_t)(kt + rb + srow) * 64 + schk * 8],
                     &Ks[b][rb * 64]);
            gl_lds16(&baseT[(size_t)(rb + srow) * 2048 + kt + schk * 8],
                     &Vt[b][rb * 64]);
        }
    };

    stage(0, 0);
    __syncthreads();

    // exp(z*0.125) = exp2(z * 0.125*log2e); clamp 60*log2e = 86.56
    const float C = 0.18033688011112042f;

    int buf = 0;
    for (int kt = 0; kt < 2048; kt += 64) {
        if (kt + 64 < 2048) stage(buf ^ 1, kt + 64);

#pragma unroll
        for (int nt = 0; nt < 4; nt++) {
            int row = nt * 16 + lr, rsw = row & 7;
            bf16x8 b0 = *(const bf16x8*)&Ks[buf][row * 64 + ((quad ^ rsw) * 8)];
            bf16x8 b1 = *(const bf16x8*)&Ks[buf][row * 64 + (((quad + 4) ^ rsw) * 8)];
#pragma unroll
            for (int f = 0; f < 2; f++) {
                floatx4 z = (floatx4){0.f, 0.f, 0.f, 0.f};
                // swapped operands: z = S^T tile; lane holds k = nt*16+quad*4+r
                // (rows) for q-row = lr (col).
                z = __builtin_amdgcn_mfma_f32_16x16x32_bf16(b0, af[f][0], z, 0, 0, 0);
                z = __builtin_amdgcn_mfma_f32_16x16x32_bf16(b1, af[f][1], z, 0, 0, 0);
                float p0 = exp2f(fminf(z[0] * C, 86.56f));
                float p1 = exp2f(fminf(z[1] * C, 86.56f));
                float p2 = exp2f(fminf(z[2] * C, 86.56f));
                float p3 = exp2f(fminf(z[3] * C, 86.56f));
                lsum[f] += (p0 + p1) + (p2 + p3);
                unsigned int lo, hi;
                asm("v_cvt_pk_bf16_f32 %0, %1, %2" : "=v"(lo) : "v"(p0), "v"(p1));
                asm("v_cvt_pk_bf16_f32 %0, %1, %2" : "=v"(hi) : "v"(p2), "v"(p3));
                uint2 pk; pk.x = lo; pk.y = hi;
                *(uint2*)&Ps[wid][f][lr][nt * 16 + quad * 4] = pk;
            }
        }

        bf16x8 aP[2][2];
#pragma unroll
        for (int f = 0; f < 2; f++) {
            aP[f][0] = *(const bf16x8*)&Ps[wid][f][lr][quad * 8];
            aP[f][1] = *(const bf16x8*)&Ps[wid][f][lr][quad * 8 + 32];
        }
        __builtin_amdgcn_s_setprio(1);
#pragma unroll
        for (int dt = 0; dt < 4; dt++) {
            int d = dt * 16 + lr, dsw = d & 7;
            bf16x8 b0 = *(const bf16x8*)&Vt[buf][d * 64 + ((quad ^ dsw) * 8)];
            bf16x8 b1 = *(const bf16x8*)&Vt[buf][d * 64 + (((quad + 4) ^ dsw) * 8)];
#pragma unroll
            for (int f = 0; f < 2; f++) {
                Of[f][dt] = __builtin_amdgcn_mfma_f32_16x16x32_bf16(aP[f][0], b0, Of[f][dt], 0, 0, 0);
                Of[f][dt] = __builtin_amdgcn_mfma_f32_16x16x32_bf16(aP[f][1], b1, Of[f][dt], 0, 0, 0);
            }
        }
        __builtin_amdgcn_s_setprio(0);

        __syncthreads();
        buf ^= 1;
    }

    const int b = bh >> 4, h = bh & 15;
#pragma unroll
    for (int f = 0; f < 2; f++) {
        float l = lsum[f];
        l += __shfl_xor(l, 16);
        l += __shfl_xor(l, 32);
#pragma unroll
        for (int r = 0; r < 4; r++) {
            float lq = __shfl(l, quad * 4 + r);
            float inv = 1.f / lq;
            size_t rowoff = ((size_t)b * 2048 + q0 + f * 64 + quad * 4 + r) * 1024 + h * 64;
#pragma unroll
            for (int dt = 0; dt < 4; dt++)
                ctx[rowoff + dt * 16 + lr] = f2bf_u(Of[f][dt][r] * inv);
        }
    }
}

// ---------------------------------------------------------------------------
// LayerNorm D=1024; input bf16 (icode 0) or fp32 (icode 1); out fp32/bf16.
__global__ __launch_bounds__(256) void ln_k(const void* __restrict__ in,
                                            const float* __restrict__ g,
                                            const float* __restrict__ b,
                                            float* __restrict__ out_f,
                                            u16* __restrict__ out_bf, int icode)
{
    const int row = blockIdx.x;
    const int t = threadIdx.x;
    float4 v;
    if (icode) {
        v = *(const float4*)&((const float*)in)[(size_t)row * 1024 + t * 4];
    } else {
        ushort4 u = *(const ushort4*)&((const u16*)in)[(size_t)row * 1024 + t * 4];
        v.x = bf2f_u(u.x); v.y = bf2f_u(u.y); v.z = bf2f_u(u.z); v.w = bf2f_u(u.w);
    }
    float s  = v.x + v.y + v.z + v.w;
    float ss = v.x * v.x + v.y * v.y + v.z * v.z + v.w * v.w;
#pragma unroll
    for (int off = 32; off >= 1; off >>= 1) {
        s  += __shfl_down(s, off);
        ss += __shfl_down(ss, off);
    }
    __shared__ float sm[10];
    const int wid = t >> 6, lane = t & 63;
    if (lane == 0) { sm[wid] = s; sm[4 + wid] = ss; }
    __syncthreads();
    if (t == 0) {
        float S  = sm[0] + sm[1] + sm[2] + sm[3];
        float SS = sm[4] + sm[5] + sm[6] + sm[7];
        float mu = S * (1.f / 1024.f);
        float var = SS * (1.f / 1024.f) - mu * mu;
        sm[8] = mu; sm[9] = rsqrtf(fmaxf(var, 0.f) + 1e-5f);
    }
    __syncthreads();
    float mu = sm[8], rs = sm[9];
    float4 G  = *(const float4*)&g[t * 4];
    float4 Bv = *(const float4*)&b[t * 4];
    float r0 = (v.x - mu) * rs * G.x + Bv.x;
    float r1 = (v.y - mu) * rs * G.y + Bv.y;
    float r2 = (v.z - mu) * rs * G.z + Bv.z;
    float r3 = (v.w - mu) * rs * G.w + Bv.w;
    if (out_f) {
        float4 ov = {r0, r1, r2, r3};
        *(float4*)&out_f[(size_t)row * 1024 + t * 4] = ov;
    }
    if (out_bf) {
        ushort4 ou = {f2bf_u(r0), f2bf_u(r1), f2bf_u(r2), f2bf_u(r3)};
        *(ushort4*)&out_bf[(size_t)row * 1024 + t * 4] = ou;
    }
}

// ---------------------------------------------------------------------------
extern "C" void kernel_launch(void* const* d_in, const int* in_sizes, int n_in,
                              void* d_out, int out_size, void* d_ws, size_t ws_size,
                              hipStream_t stream)
{
    const float* x    = (const float*)d_in[0];
    const float* wq_w = (const float*)d_in[1];
    const float* wq_b = (const float*)d_in[2];
    const float* fc_w = (const float*)d_in[3];
    const float* fc_b = (const float*)d_in[4];
    const float* ln1g = (const float*)d_in[5];
    const float* ln1b = (const float*)d_in[6];
    const float* w1   = (const float*)d_in[7];
    const float* b1   = (const float*)d_in[8];
    const float* w2   = (const float*)d_in[9];
    const float* b2   = (const float*)d_in[10];
    const float* ln2g = (const float*)d_in[11];
    const float* ln2b = (const float*)d_in[12];

    // Workspace layout (see round-0 comment); qhT shares [44,52) with yfc_bf.
    char* ws = (char*)d_ws;
    const size_t MB = 1024 * 1024;
    u16*   w1_bt  = (u16*)(ws);
    u16*   w2_bt  = (u16*)(ws + 8 * MB);
    u16*   wqm_bt = (u16*)(ws + 16 * MB);
    u16*   fcw_bt = (u16*)(ws + 18 * MB);
    u16*   x_bf   = (u16*)(ws + 20 * MB);
    u16*   qh     = (u16*)(ws + 28 * MB);
    u16*   yln1   = (u16*)(ws + 28 * MB);
    u16*   ctx    = (u16*)(ws + 36 * MB);
    u16*   yfc_bf = (u16*)(ws + 44 * MB);
    u16*   qhT    = (u16*)(ws + 44 * MB);   // shared with yfc_bf (disjoint)
    u16*   h1     = (u16*)(ws + 36 * MB);   // full or chunk base
    float* z      = (float*)d_out;
    const bool fullN = ws_size >= 69 * MB;

    // fused prep: 4 transposes + tobf in one launch
    prep_k<<<4608, 256, 0, stream>>>(x, x_bf, w1, w1_bt, w2, w2_bt,
                                     wq_w, wqm_bt, fc_w, fcw_bt);

    // qproj: x_bf @ wqm_bt^T + wq_b -> qh scatter   (depth-3, 512 blk)
    gemm_bt64p3_k<<<512, 256, 0, stream>>>(x_bf, wqm_bt, 32, 16, 1024, 1024, 1024,
                                           wq_b, nullptr, nullptr, qh, 0);
    // V transpose for attn: qhT[bh][d][s]
    transpose_qh_k<<<dim3(32, 32), 256, 0, stream>>>(qh, qhT);
    // attn v5r: QBLK=128, 512 blocks
    attn_mfma_k<<<512, 256, 0, stream>>>(qh, qhT, ctx);
    // fc: ctx @ fcw_bt^T + fc_b + x_bf -> yfc_bf    (depth-3, 512 blk)
    gemm_bt64p3_k<<<512, 256, 0, stream>>>(ctx, fcw_bt, 32, 16, 1024, 1024, 1024,
                                           fc_b, x_bf, nullptr, yfc_bf, 4);
    ln_k<<<4096, 256, 0, stream>>>(yfc_bf, ln1g, ln1b, nullptr, yln1, 0);

    if (fullN) {
        // mlp1: yln1 @ w1_bt^T -> relu -> h1 [4096,4096]
        // (BM=64: gm=64 gn=64, grid 4096 = 5 resident blocks/CU)
        gemm_bt64m_k<<<4096, 256, 0, stream>>>(yln1, w1_bt, 64, 64, 4096, 1024, 1024,
                                               b1, nullptr, nullptr, h1, 2);
        // mlp2: h1 @ w2_bt^T + b2 + yln1 -> z fp32
        // (BM=64: gm=64 gn=16, grid 1024 = 4 blocks/CU)
        gemm_bt64m_k<<<1024, 256, 0, stream>>>(h1, w2_bt, 64, 16, 1024, 4096, 4096,
                                               b2, yln1, z, nullptr, 1);
    } else {
        gemm_bt64m_k<<<2048, 256, 0, stream>>>(yln1, w1_bt, 64, 32, 2048, 1024, 1024,
                                               b1, nullptr, nullptr, h1, 2);
        gemm_bt64m_k<<<1024, 256, 0, stream>>>(h1, w2_bt, 64, 16, 1024, 2048, 4096,
                                               b2, yln1, z, nullptr, 1);
        gemm_bt64m_k<<<2048, 256, 0, stream>>>(yln1, w1_bt + (size_t)2048 * 1024, 64, 32,
                                               2048, 1024, 1024,
                                               b1 + 2048, nullptr, nullptr, h1, 2);
        gemm_bt64m_k<<<1024, 256, 0, stream>>>(h1, w2_bt + 2048, 64, 16, 1024, 2048, 4096,
                                               nullptr, nullptr, z, nullptr, 3);
    }
    ln_k<<<4096, 256, 0, stream>>>(z, ln2g, ln2b, (float*)d_out, nullptr, 1);
}

// Round 21
// 360.179 us; speedup vs baseline: 1.0660x; 1.0405x over previous
//
#include <hip/hip_runtime.h>
#include <hip/hip_bf16.h>

typedef unsigned short u16;
typedef __bf16 bf16x8 __attribute__((ext_vector_type(8)));
typedef float floatx4 __attribute__((ext_vector_type(4)));

__device__ __forceinline__ float bf2f_u(u16 u) {
    union { unsigned int i; float f; } x; x.i = ((unsigned int)u) << 16; return x.f;
}
__device__ __forceinline__ u16 f2bf_u(float f) {
    union { float f; unsigned int i; } x; x.f = f;
    unsigned int r = x.i + 0x7fffu + ((x.i >> 16) & 1u);   // RNE
    return (u16)(r >> 16);
}

// async global->LDS, 16 B/lane, LDS dest = wave-uniform base + lane*16
__device__ __forceinline__ void gl_lds16(const void* g, void* l) {
    __builtin_amdgcn_global_load_lds(
        (const __attribute__((address_space(1))) void*)g,
        (__attribute__((address_space(3))) void*)l, 16, 0, 0);
}

// ---------------------------------------------------------------------------
// Fused prep kernel: replaces 4x transpose + tobf (5 launches -> 1).
__device__ __forceinline__ void transpose_body(
    const float* __restrict__ ip, u16* __restrict__ op,
    int R, int C, int r0, int c0, int t, u16 (*T)[80])
{
#pragma unroll
    for (int i = 0; i < 4; i++) {
        int c = t + i * 256;
        int rr = c >> 4, cc = (c & 15) * 4;
        float4 v = *(const float4*)&ip[(size_t)(r0 + rr) * C + c0 + cc];
        T[cc + 0][rr] = f2bf_u(v.x); T[cc + 1][rr] = f2bf_u(v.y);
        T[cc + 2][rr] = f2bf_u(v.z); T[cc + 3][rr] = f2bf_u(v.w);
    }
    __syncthreads();
#pragma unroll
    for (int i = 0; i < 2; i++) {
        int c = t + i * 256;
        int oc = c >> 3, k8 = (c & 7) * 8;
        uint4 v = *(const uint4*)&T[oc][k8];
        *(uint4*)&op[(size_t)(c0 + oc) * R + r0 + k8] = v;
    }
}

__global__ __launch_bounds__(256) void prep_k(
    const float* __restrict__ x,    u16* __restrict__ x_bf,
    const float* __restrict__ w1,   u16* __restrict__ w1_bt,
    const float* __restrict__ w2,   u16* __restrict__ w2_bt,
    const float* __restrict__ wq_w, u16* __restrict__ wqm_bt,
    const float* __restrict__ fc_w, u16* __restrict__ fcw_bt)
{
    __shared__ u16 T[64][80];
    const int id = blockIdx.x, t = threadIdx.x;
    if (id < 2048) {
        int i = (id * 256 + t) * 8;
        float4 v0 = *(const float4*)&x[i];
        float4 v1 = *(const float4*)&x[i + 4];
        u16 tmp[8] = {f2bf_u(v0.x), f2bf_u(v0.y), f2bf_u(v0.z), f2bf_u(v0.w),
                      f2bf_u(v1.x), f2bf_u(v1.y), f2bf_u(v1.z), f2bf_u(v1.w)};
        *(uint4*)&x_bf[i] = *(const uint4*)tmp;
    } else if (id < 3072) {
        int j = id - 2048;                       // grid (64,16)
        transpose_body(w1, w1_bt, 1024, 4096, (j >> 6) * 64, (j & 63) * 64, t, T);
    } else if (id < 4096) {
        int j = id - 3072;                       // grid (16,64)
        transpose_body(w2, w2_bt, 4096, 1024, (j >> 4) * 64, (j & 15) * 64, t, T);
    } else if (id < 4352) {
        int j = id - 4096;                       // grid (1,16,16): y=j&15, z=j>>4
        int z = j >> 4;
        transpose_body(wq_w + (size_t)z * (1024 * 64),
                       wqm_bt + (size_t)z * (64 * 1024),
                       1024, 64, (j & 15) * 64, 0, t, T);
    } else {
        int j = id - 4352;                       // grid (16,16)
        transpose_body(fc_w, fcw_bt, 1024, 1024, (j >> 4) * 64, (j & 15) * 64, t, T);
    }
}

// ---------------------------------------------------------------------------
// bf16 transpose for attention V: qhT[bh][d][s] = qh[bh][s][d].
__global__ __launch_bounds__(256) void transpose_qh_k(const u16* __restrict__ in,
                                                      u16* __restrict__ out)
{
    __shared__ u16 T[64][72];            // 72*2B = 144 B row = 9x16B (aligned)
    const int bh = blockIdx.y;
    const int s0 = blockIdx.x * 64;
    const u16* ip = in + (size_t)bh * (2048 * 64);
    u16* op = out + (size_t)bh * (64 * 2048);
    const int t = threadIdx.x;
#pragma unroll
    for (int i = 0; i < 2; i++) {
        int c = t + i * 256;             // 512 chunks of 8 u16
        int r = c >> 3, cc = (c & 7) * 8;
        uint4 v = *(const uint4*)&ip[(size_t)(s0 + r) * 64 + cc];
        const u16* pv = (const u16*)&v;
#pragma unroll
        for (int k = 0; k < 8; k++) T[cc + k][r] = pv[k];
    }
    __syncthreads();
#pragma unroll
    for (int i = 0; i < 2; i++) {
        int c = t + i * 256;
        int d = c >> 3, cs = (c & 7) * 8;
        uint4 v = *(const uint4*)&T[d][cs];
        *(uint4*)&op[(size_t)d * 2048 + s0 + cs] = v;
    }
}

// ---------------------------------------------------------------------------
// Shared epilogue (4x2 acc) for BM=128 GEMMs.
__device__ __forceinline__ void gemm_epilogue(
    floatx4 (&acc)[4][2], int m0, int n0, int wm, int wn, int lr, int quad,
    int N, const float* __restrict__ bias, const u16* __restrict__ resid,
    float* __restrict__ out, u16* __restrict__ out_bf, int mode)
{
#pragma unroll
    for (int i = 0; i < 4; i++) {
#pragma unroll
        for (int j = 0; j < 2; j++) {
#pragma unroll
            for (int r = 0; r < 4; r++) {
                int grow = m0 + wm + i * 16 + quad * 4 + r;
                int gcol = n0 + wn + j * 16 + lr;
                float val = acc[i][j][r];
                if (bias) val += bias[gcol];
                if (mode == 0) {
                    int bb = grow >> 11, ss = grow & 2047;
                    int h = gcol >> 6, e = gcol & 63;
                    out_bf[(((size_t)bb * 16 + h) * 2048 + ss) * 64 + e] = f2bf_u(val);
                } else if (mode == 1) {
                    size_t idx = (size_t)grow * N + gcol;
                    out[idx] = val + bf2f_u(resid[idx]);
                } else if (mode == 2) {
                    out_bf[(size_t)grow * N + gcol] = f2bf_u(fmaxf(val, 0.f));
                } else if (mode == 3) {
                    size_t idx = (size_t)grow * N + gcol;
                    out[idx] = out[idx] + val;
                } else {  // mode 4
                    size_t idx = (size_t)grow * N + gcol;
                    out_bf[idx] = f2bf_u(val + bf2f_u(resid[idx]));
                }
            }
        }
    }
}

// ---------------------------------------------------------------------------
// Depth-3 counted-vmcnt BM=128 variant (qproj / fc). 72 KB LDS, 2 blocks/CU.
__global__ __launch_bounds__(256) void gemm_bt64p3_k(
    const u16* __restrict__ A, const u16* __restrict__ Bt,
    int gm, int gn, int N, int K, int ldb,
    const float* __restrict__ bias, const u16* __restrict__ resid,
    float* __restrict__ out, u16* __restrict__ out_bf, int mode)
{
    __shared__ __align__(16) u16 As[3][128 * 64];
    __shared__ __align__(16) u16 Bs[3][64 * 64];

    const int id = blockIdx.x;
    const int xcd = id & 7, s = id >> 3;
    const int bandM = gm >> 2, bandN = gn >> 1;
    const int m0 = ((xcd >> 1) * bandM + (s % bandM)) * 128;
    const int n0 = ((xcd & 1) * bandN + (s / bandM)) * 64;

    const int t = threadIdx.x;
    const int wid = t >> 6, lane = t & 63;
    const int wm = (wid >> 1) * 64, wn = (wid & 1) * 32;
    const int lr = lane & 15, quad = lane >> 4;
    const int srow = lane >> 3;
    const int scol = ((lane & 7) ^ (lane >> 3)) * 8;

    floatx4 acc[4][2];
#pragma unroll
    for (int i = 0; i < 4; i++)
#pragma unroll
        for (int j = 0; j < 2; j++)
            acc[i][j] = (floatx4){0.f, 0.f, 0.f, 0.f};

    auto stage = [&](int b, int k0) {
#pragma unroll
        for (int i = 0; i < 4; i++) {
            int rb = wid * 32 + i * 8;
            gl_lds16(&A[(size_t)(m0 + rb + srow) * K + k0 + scol], &As[b][rb * 64]);
        }
#pragma unroll
        for (int i = 0; i < 2; i++) {
            int rb = wid * 16 + i * 8;
            gl_lds16(&Bt[(size_t)(n0 + rb + srow) * ldb + k0 + scol], &Bs[b][rb * 64]);
        }
    };

    const int nt = K >> 6;
    stage(0, 0);
    stage(1, 64);

    int cur = 0, nxt = 2;
    for (int tt = 0; tt < nt; tt++) {
        if (tt + 1 < nt) asm volatile("s_waitcnt vmcnt(6)" ::: "memory");
        else             asm volatile("s_waitcnt vmcnt(0)" ::: "memory");
        __builtin_amdgcn_s_barrier();
        __builtin_amdgcn_sched_barrier(0);
        if (tt + 2 < nt) stage(nxt, (tt + 2) * 64);

#pragma unroll
        for (int kk = 0; kk < 2; kk++) {
            bf16x8 af[4], bfr[2];
#pragma unroll
            for (int i = 0; i < 4; i++) {
                int R = wm + i * 16 + lr;
                int c = ((kk * 4 + quad) ^ (lr & 7)) * 8;
                af[i] = *(const bf16x8*)&As[cur][R * 64 + c];
            }
#pragma unroll
            for (int j = 0; j < 2; j++) {
                int R = wn + j * 16 + lr;
                int c = ((kk * 4 + quad) ^ (lr & 7)) * 8;
                bfr[j] = *(const bf16x8*)&Bs[cur][R * 64 + c];
            }
#pragma unroll
            for (int i = 0; i < 4; i++)
#pragma unroll
                for (int j = 0; j < 2; j++)
                    acc[i][j] = __builtin_amdgcn_mfma_f32_16x16x32_bf16(af[i], bfr[j], acc[i][j], 0, 0, 0);
        }
        cur = (cur == 2) ? 0 : cur + 1;
        nxt = (nxt == 2) ? 0 : nxt + 1;
    }

    gemm_epilogue(acc, m0, n0, wm, wn, lr, quad, N, bias, resid, out, out_bf, mode);
}

// ---------------------------------------------------------------------------
// BM=64/BN=64 double-buffered GEMM (mlp1 AND mlp2). Block TLP is the lever
// (r16/r17): 32 KB LDS dbuf -> up to 5 resident blocks/CU.
__global__ __launch_bounds__(256) void gemm_bt64m_k(
    const u16* __restrict__ A, const u16* __restrict__ Bt,
    int gm, int gn, int N, int K, int ldb,
    const float* __restrict__ bias, const u16* __restrict__ resid,
    float* __restrict__ out, u16* __restrict__ out_bf, int mode)
{
    __shared__ __align__(16) u16 As[2][64 * 64];
    __shared__ __align__(16) u16 Bs[2][64 * 64];

    // XCD swizzle: gm x gn tile grid, 8 rectangles
    const int id = blockIdx.x;
    const int xcd = id & 7, s = id >> 3;
    const int bandM = gm >> 2, bandN = gn >> 1;
    const int m0 = ((xcd >> 1) * bandM + (s % bandM)) * 64;
    const int n0 = ((xcd & 1) * bandN + (s / bandM)) * 64;

    const int t = threadIdx.x;
    const int wid = t >> 6, lane = t & 63;
    const int wm = (wid >> 1) * 32, wn = (wid & 1) * 32;
    const int lr = lane & 15, quad = lane >> 4;
    const int srow = lane >> 3;
    const int scol = ((lane & 7) ^ (lane >> 3)) * 8;   // inverse-swizzled source

    floatx4 acc[2][2];
#pragma unroll
    for (int i = 0; i < 2; i++)
#pragma unroll
        for (int j = 0; j < 2; j++)
            acc[i][j] = (floatx4){0.f, 0.f, 0.f, 0.f};

    auto stage = [&](int b, int k0) {
#pragma unroll
        for (int i = 0; i < 2; i++) {                  // A: 64 rows, 2/wave
            int rb = wid * 16 + i * 8;
            gl_lds16(&A[(size_t)(m0 + rb + srow) * K + k0 + scol], &As[b][rb * 64]);
        }
#pragma unroll
        for (int i = 0; i < 2; i++) {                  // B: 64 rows, 2/wave
            int rb = wid * 16 + i * 8;
            gl_lds16(&Bt[(size_t)(n0 + rb + srow) * ldb + k0 + scol], &Bs[b][rb * 64]);
        }
    };

    const int nt = K >> 6;
    stage(0, 0);

    int cur = 0;
    for (int tt = 0; tt < nt; tt++) {
        asm volatile("s_waitcnt vmcnt(0)" ::: "memory");
        __builtin_amdgcn_s_barrier();
        __builtin_amdgcn_sched_barrier(0);
        if (tt + 1 < nt) stage(cur ^ 1, (tt + 1) * 64);

#pragma unroll
        for (int kk = 0; kk < 2; kk++) {
            bf16x8 af[2], bfr[2];
#pragma unroll
            for (int i = 0; i < 2; i++) {
                int R = wm + i * 16 + lr;
                int c = ((kk * 4 + quad) ^ (lr & 7)) * 8;
                af[i] = *(const bf16x8*)&As[cur][R * 64 + c];
            }
#pragma unroll
            for (int j = 0; j < 2; j++) {
                int R = wn + j * 16 + lr;
                int c = ((kk * 4 + quad) ^ (lr & 7)) * 8;
                bfr[j] = *(const bf16x8*)&Bs[cur][R * 64 + c];
            }
#pragma unroll
            for (int i = 0; i < 2; i++)
#pragma unroll
                for (int j = 0; j < 2; j++)
                    acc[i][j] = __builtin_amdgcn_mfma_f32_16x16x32_bf16(af[i], bfr[j], acc[i][j], 0, 0, 0);
        }
        cur ^= 1;
    }

    // epilogue (2x2 acc)
#pragma unroll
    for (int i = 0; i < 2; i++) {
#pragma unroll
        for (int j = 0; j < 2; j++) {
#pragma unroll
            for (int r = 0; r < 4; r++) {
                int grow = m0 + wm + i * 16 + quad * 4 + r;
                int gcol = n0 + wn + j * 16 + lr;
                float val = acc[i][j][r];
                if (bias) val += bias[gcol];
                if (mode == 1) {
                    size_t idx = (size_t)grow * N + gcol;
                    out[idx] = val + bf2f_u(resid[idx]);
                } else if (mode == 3) {
                    size_t idx = (size_t)grow * N + gcol;
                    out[idx] = out[idx] + val;
                } else {  // mode 2
                    out_bf[(size_t)grow * N + gcol] = f2bf_u(fmaxf(val, 0.f));
                }
            }
        }
    }
}

// ---------------------------------------------------------------------------
// MFMA flash attention v5 (r18 source, best validated: attn 68.5 µs, total
// 361.5). r20 lesson: plain exp2f is the PRECISE libm entry (hipcc emits
// range-fixup VALU around v_exp_f32) — it cost +12.7 µs vs __expf. Keep
// __expf (fast intrinsic: v_mul + v_exp_f32). QBLK=128 (QBLK=64 regressed
// twice: staging the full K/V stream per block dominates when halved).
#define PST 68
__global__ __launch_bounds__(256) void attn_mfma_k(const u16* __restrict__ qh,
                                                   const u16* __restrict__ qhT,
                                                   u16* __restrict__ ctx)
{
    __shared__ __align__(16) u16 Ks[2][64 * 64];
    __shared__ __align__(16) u16 Vt[2][64 * 64];
    __shared__ __align__(16) u16 Ps[4][2][16][PST];

    const int bh = blockIdx.x >> 4;
    const int qb = blockIdx.x & 15;
    const u16* __restrict__ base  = qh  + (size_t)bh * (2048 * 64);
    const u16* __restrict__ baseT = qhT + (size_t)bh * (64 * 2048);
    const int t = threadIdx.x, wid = t >> 6, lane = t & 63;
    const int lr = lane & 15, quad = lane >> 4;
    const int q0 = qb * 128 + wid * 16;

    bf16x8 af[2][2];
#pragma unroll
    for (int f = 0; f < 2; f++) {
        af[f][0] = *(const bf16x8*)&base[(size_t)(q0 + f * 64 + lr) * 64 + quad * 8];
        af[f][1] = *(const bf16x8*)&base[(size_t)(q0 + f * 64 + lr) * 64 + quad * 8 + 32];
    }

    floatx4 Of[2][4];
#pragma unroll
    for (int f = 0; f < 2; f++)
#pragma unroll
        for (int dt = 0; dt < 4; dt++) Of[f][dt] = (floatx4){0.f, 0.f, 0.f, 0.f};
    float lsum[2] = {0.f, 0.f};

    const int srow = lane >> 3;
    const int schk = (lane & 7) ^ srow;

    auto stage = [&](int b, int kt) {
#pragma unroll
        for (int i = 0; i < 2; i++) {
            int rb = (wid * 2 + i) * 8;
            gl_lds16(&base[(size_t)(kt + rb + srow) * 64 + schk * 8],
                     &Ks[b][rb * 64]);
            gl_lds16(&baseT[(size_t)(rb + srow) * 2048 + kt + schk * 8],
                     &Vt[b][rb * 64]);
        }
    };

    stage(0, 0);
    __syncthreads();

    int buf = 0;
    for (int kt = 0; kt < 2048; kt += 64) {
        if (kt + 64 < 2048) stage(buf ^ 1, kt + 64);

#pragma unroll
        for (int nt = 0; nt < 4; nt++) {
            int row = nt * 16 + lr, rsw = row & 7;
            bf16x8 b0 = *(const bf16x8*)&Ks[buf][row * 64 + ((quad ^ rsw) * 8)];
            bf16x8 b1 = *(const bf16x8*)&Ks[buf][row * 64 + (((quad + 4) ^ rsw) * 8)];
#pragma unroll
            for (int f = 0; f < 2; f++) {
                floatx4 z = (floatx4){0.f, 0.f, 0.f, 0.f};
                z = __builtin_amdgcn_mfma_f32_16x16x32_bf16(b0, af[f][0], z, 0, 0, 0);
                z = __builtin_amdgcn_mfma_f32_16x16x32_bf16(b1, af[f][1], z, 0, 0, 0);
                float p0 = __expf(fminf(z[0] * 0.125f, 60.f));
                float p1 = __expf(fminf(z[1] * 0.125f, 60.f));
                float p2 = __expf(fminf(z[2] * 0.125f, 60.f));
                float p3 = __expf(fminf(z[3] * 0.125f, 60.f));
                lsum[f] += (p0 + p1) + (p2 + p3);
                unsigned int lo, hi;
                asm("v_cvt_pk_bf16_f32 %0, %1, %2" : "=v"(lo) : "v"(p0), "v"(p1));
                asm("v_cvt_pk_bf16_f32 %0, %1, %2" : "=v"(hi) : "v"(p2), "v"(p3));
                uint2 pk; pk.x = lo; pk.y = hi;
                *(uint2*)&Ps[wid][f][lr][nt * 16 + quad * 4] = pk;
            }
        }

        bf16x8 aP[2][2];
#pragma unroll
        for (int f = 0; f < 2; f++) {
            aP[f][0] = *(const bf16x8*)&Ps[wid][f][lr][quad * 8];
            aP[f][1] = *(const bf16x8*)&Ps[wid][f][lr][quad * 8 + 32];
        }
        __builtin_amdgcn_s_setprio(1);
#pragma unroll
        for (int dt = 0; dt < 4; dt++) {
            int d = dt * 16 + lr, dsw = d & 7;
            bf16x8 b0 = *(const bf16x8*)&Vt[buf][d * 64 + ((quad ^ dsw) * 8)];
            bf16x8 b1 = *(const bf16x8*)&Vt[buf][d * 64 + (((quad + 4) ^ dsw) * 8)];
#pragma unroll
            for (int f = 0; f < 2; f++) {
                Of[f][dt] = __builtin_amdgcn_mfma_f32_16x16x32_bf16(aP[f][0], b0, Of[f][dt], 0, 0, 0);
                Of[f][dt] = __builtin_amdgcn_mfma_f32_16x16x32_bf16(aP[f][1], b1, Of[f][dt], 0, 0, 0);
            }
        }
        __builtin_amdgcn_s_setprio(0);

        __syncthreads();
        buf ^= 1;
    }

    const int b = bh >> 4, h = bh & 15;
#pragma unroll
    for (int f = 0; f < 2; f++) {
        float l = lsum[f];
        l += __shfl_xor(l, 16);
        l += __shfl_xor(l, 32);
#pragma unroll
        for (int r = 0; r < 4; r++) {
            float lq = __shfl(l, quad * 4 + r);
            float inv = 1.f / lq;
            size_t rowoff = ((size_t)b * 2048 + q0 + f * 64 + quad * 4 + r) * 1024 + h * 64;
#pragma unroll
            for (int dt = 0; dt < 4; dt++)
                ctx[rowoff + dt * 16 + lr] = f2bf_u(Of[f][dt][r] * inv);
        }
    }
}

// ---------------------------------------------------------------------------
// LayerNorm D=1024; input bf16 (icode 0) or fp32 (icode 1); out fp32/bf16.
__global__ __launch_bounds__(256) void ln_k(const void* __restrict__ in,
                                            const float* __restrict__ g,
                                            const float* __restrict__ b,
                                            float* __restrict__ out_f,
                                            u16* __restrict__ out_bf, int icode)
{
    const int row = blockIdx.x;
    const int t = threadIdx.x;
    float4 v;
    if (icode) {
        v = *(const float4*)&((const float*)in)[(size_t)row * 1024 + t * 4];
    } else {
        ushort4 u = *(const ushort4*)&((const u16*)in)[(size_t)row * 1024 + t * 4];
        v.x = bf2f_u(u.x); v.y = bf2f_u(u.y); v.z = bf2f_u(u.z); v.w = bf2f_u(u.w);
    }
    float s  = v.x + v.y + v.z + v.w;
    float ss = v.x * v.x + v.y * v.y + v.z * v.z + v.w * v.w;
#pragma unroll
    for (int off = 32; off >= 1; off >>= 1) {
        s  += __shfl_down(s, off);
        ss += __shfl_down(ss, off);
    }
    __shared__ float sm[10];
    const int wid = t >> 6, lane = t & 63;
    if (lane == 0) { sm[wid] = s; sm[4 + wid] = ss; }
    __syncthreads();
    if (t == 0) {
        float S  = sm[0] + sm[1] + sm[2] + sm[3];
        float SS = sm[4] + sm[5] + sm[6] + sm[7];
        float mu = S * (1.f / 1024.f);
        float var = SS * (1.f / 1024.f) - mu * mu;
        sm[8] = mu; sm[9] = rsqrtf(fmaxf(var, 0.f) + 1e-5f);
    }
    __syncthreads();
    float mu = sm[8], rs = sm[9];
    float4 G  = *(const float4*)&g[t * 4];
    float4 Bv = *(const float4*)&b[t * 4];
    float r0 = (v.x - mu) * rs * G.x + Bv.x;
    float r1 = (v.y - mu) * rs * G.y + Bv.y;
    float r2 = (v.z - mu) * rs * G.z + Bv.z;
    float r3 = (v.w - mu) * rs * G.w + Bv.w;
    if (out_f) {
        float4 ov = {r0, r1, r2, r3};
        *(float4*)&out_f[(size_t)row * 1024 + t * 4] = ov;
    }
    if (out_bf) {
        ushort4 ou = {f2bf_u(r0), f2bf_u(r1), f2bf_u(r2), f2bf_u(r3)};
        *(ushort4*)&out_bf[(size_t)row * 1024 + t * 4] = ou;
    }
}

// ---------------------------------------------------------------------------
extern "C" void kernel_launch(void* const* d_in, const int* in_sizes, int n_in,
                              void* d_out, int out_size, void* d_ws, size_t ws_size,
                              hipStream_t stream)
{
    const float* x    = (const float*)d_in[0];
    const float* wq_w = (const float*)d_in[1];
    const float* wq_b = (const float*)d_in[2];
    const float* fc_w = (const float*)d_in[3];
    const float* fc_b = (const float*)d_in[4];
    const float* ln1g = (const float*)d_in[5];
    const float* ln1b = (const float*)d_in[6];
    const float* w1   = (const float*)d_in[7];
    const float* b1   = (const float*)d_in[8];
    const float* w2   = (const float*)d_in[9];
    const float* b2   = (const float*)d_in[10];
    const float* ln2g = (const float*)d_in[11];
    const float* ln2b = (const float*)d_in[12];

    // Workspace layout (see round-0 comment); qhT shares [44,52) with yfc_bf.
    char* ws = (char*)d_ws;
    const size_t MB = 1024 * 1024;
    u16*   w1_bt  = (u16*)(ws);
    u16*   w2_bt  = (u16*)(ws + 8 * MB);
    u16*   wqm_bt = (u16*)(ws + 16 * MB);
    u16*   fcw_bt = (u16*)(ws + 18 * MB);
    u16*   x_bf   = (u16*)(ws + 20 * MB);
    u16*   qh     = (u16*)(ws + 28 * MB);
    u16*   yln1   = (u16*)(ws + 28 * MB);
    u16*   ctx    = (u16*)(ws + 36 * MB);
    u16*   yfc_bf = (u16*)(ws + 44 * MB);
    u16*   qhT    = (u16*)(ws + 44 * MB);   // shared with yfc_bf (disjoint)
    u16*   h1     = (u16*)(ws + 36 * MB);   // full or chunk base
    float* z      = (float*)d_out;
    const bool fullN = ws_size >= 69 * MB;

    // fused prep: 4 transposes + tobf in one launch
    prep_k<<<4608, 256, 0, stream>>>(x, x_bf, w1, w1_bt, w2, w2_bt,
                                     wq_w, wqm_bt, fc_w, fcw_bt);

    // qproj: x_bf @ wqm_bt^T + wq_b -> qh scatter   (depth-3, 512 blk)
    gemm_bt64p3_k<<<512, 256, 0, stream>>>(x_bf, wqm_bt, 32, 16, 1024, 1024, 1024,
                                           wq_b, nullptr, nullptr, qh, 0);
    // V transpose for attn: qhT[bh][d][s]
    transpose_qh_k<<<dim3(32, 32), 256, 0, stream>>>(qh, qhT);
    // attn v5: QBLK=128, 512 blocks
    attn_mfma_k<<<512, 256, 0, stream>>>(qh, qhT, ctx);
    // fc: ctx @ fcw_bt^T + fc_b + x_bf -> yfc_bf    (depth-3, 512 blk)
    gemm_bt64p3_k<<<512, 256, 0, stream>>>(ctx, fcw_bt, 32, 16, 1024, 1024, 1024,
                                           fc_b, x_bf, nullptr, yfc_bf, 4);
    ln_k<<<4096, 256, 0, stream>>>(yfc_bf, ln1g, ln1b, nullptr, yln1, 0);

    if (fullN) {
        // mlp1: yln1 @ w1_bt^T -> relu -> h1 [4096,4096]
        // (BM=64: gm=64 gn=64, grid 4096 = 5 resident blocks/CU)
        gemm_bt64m_k<<<4096, 256, 0, stream>>>(yln1, w1_bt, 64, 64, 4096, 1024, 1024,
                                               b1, nullptr, nullptr, h1, 2);
        // mlp2: h1 @ w2_bt^T + b2 + yln1 -> z fp32
        // (BM=64: gm=64 gn=16, grid 1024 = 4 blocks/CU)
        gemm_bt64m_k<<<1024, 256, 0, stream>>>(h1, w2_bt, 64, 16, 1024, 4096, 4096,
                                               b2, yln1, z, nullptr, 1);
    } else {
        gemm_bt64m_k<<<2048, 256, 0, stream>>>(yln1, w1_bt, 64, 32, 2048, 1024, 1024,
                                               b1, nullptr, nullptr, h1, 2);
        gemm_bt64m_k<<<1024, 256, 0, stream>>>(h1, w2_bt, 64, 16, 1024, 2048, 4096,
                                               b2, yln1, z, nullptr, 1);
        gemm_bt64m_k<<<2048, 256, 0, stream>>>(yln1, w1_bt + (size_t)2048 * 1024, 64, 32,
                                               2048, 1024, 1024,
                                               b1 + 2048, nullptr, nullptr, h1, 2);
        gemm_bt64m_k<<<1024, 256, 0, stream>>>(h1, w2_bt + 2048, 64, 16, 1024, 2048, 4096,
                                               nullptr, nullptr, z, nullptr, 3);
    }
    ln_k<<<4096, 256, 0, stream>>>(z, ln2g, ln2b, (float*)d_out, nullptr, 1);
}